// Round 9
// baseline (1056.213 us; speedup 1.0000x reference)
//
#include <hip/hip_runtime.h>
#include <hip/hip_cooperative_groups.h>
namespace cg = cooperative_groups;

#define NEG_SLOPE 0.2f
#define NPB 256          // nodes per dst-bucket (bucket = dst >> 8)
#define CHUNK 4096       // edges per partition block
#define BCAP 5120        // padded bucket capacity (expected fill 4096, +16 sigma)

typedef _Float16 f16x8 __attribute__((ext_vector_type(8)));
typedef _Float16 f16x2 __attribute__((ext_vector_type(2)));
typedef float    f32x4 __attribute__((ext_vector_type(4)));
typedef float    f32x8 __attribute__((ext_vector_type(8)));

#if defined(__has_builtin)
#if __has_builtin(__builtin_amdgcn_fdot2)
#define HAVE_FDOT2 1
#endif
#if __has_builtin(__builtin_amdgcn_exp2f)
#define FEXP2(x) __builtin_amdgcn_exp2f(x)
#endif
#endif
#ifndef FEXP2
#define FEXP2(x) exp2f(x)
#endif

// DPP butterfly add — pure VALU. 0xB1=xor1, 0x4E=xor2, 0x141=xor4(half-mirror
// once quads uniform), 0x140=xor8(mirror once 8-groups uniform).
template <int CTRL>
__device__ __forceinline__ float dpp_add(float v) {
    int o = __builtin_amdgcn_update_dpp(0, __builtin_bit_cast(int, v),
                                        CTRL, 0xF, 0xF, true);
    return v + __builtin_bit_cast(float, o);
}

// Shared-memory union across all phase bodies (36,864 B -> 4 blocks/CU).
union SharedU {
    struct { int2 pairs[CHUNK]; int bh[256]; int bbase[256]; int exb[256]; int scn[256]; } b;
    _Float16 w[128 * 136];
    struct { int lhist[256]; int lscan[256]; int lcur[256]; } s;
};

// ---------------------------------------------------------------------------
// chunk bucketing body (LDS counting-sort -> coalesced per-bucket flush)
// ---------------------------------------------------------------------------
__device__ __forceinline__ void bucket_chunk_body(
    SharedU& L, const int* __restrict__ ei, int* __restrict__ gcursor,
    int2* __restrict__ staging, int E, int bid)
{
    int t = threadIdx.x;
    L.b.bh[t] = 0;
    __syncthreads();
    int base = bid * CHUNK;
    int srcv[16], dstv[16], rb[16];
#pragma unroll
    for (int j = 0; j < 16; j++) {
        int e = base + t + j * 256;
        if (e < E) {
            int d = ei[E + e];
            srcv[j] = ei[e];
            dstv[j] = d;
            int bk = d >> 8;
            int r = atomicAdd(&L.b.bh[bk], 1);
            rb[j] = (r << 8) | bk;
        } else rb[j] = -1;
    }
    __syncthreads();
    int v = L.b.bh[t];
    L.b.scn[t] = v;
    __syncthreads();
    for (int off = 1; off < 256; off <<= 1) {
        int u = (t >= off) ? L.b.scn[t - off] : 0;
        __syncthreads();
        L.b.scn[t] += u;
        __syncthreads();
    }
    int ex = L.b.scn[t] - v;
    int tot = L.b.scn[255];
    L.b.exb[t] = ex;
    if (v) L.b.bbase[t] = t * BCAP + atomicAdd(&gcursor[t], v);
    __syncthreads();
#pragma unroll
    for (int j = 0; j < 16; j++) {
        if (rb[j] >= 0) {
            int bk = rb[j] & 255, r = rb[j] >> 8;
            L.b.pairs[L.b.exb[bk] + r] = make_int2(srcv[j], dstv[j]);
        }
    }
    __syncthreads();
    for (int i = t; i < tot; i += 256) {
        int2 p = L.b.pairs[i];
        int bk = p.y >> 8;
        staging[L.b.bbase[bk] + (i - L.b.exb[bk])] = p;
    }
}

// ---------------------------------------------------------------------------
// fp16 MFMA GEMM tile body, LDS-staged W. C = Ah@W + Al@W, fp32 acc.
// ---------------------------------------------------------------------------
__device__ __forceinline__ void gemm_body(
    const _Float16* __restrict__ Ahi, const _Float16* __restrict__ Alo,
    const _Float16* __restrict__ Wt, _Float16* __restrict__ C, int N,
    int bx, _Float16* ldsW)
{
    const int tid = threadIdx.x;
    const int wave = tid >> 6;
    const int lane = tid & 63;
    const int mrow = lane & 15;
    const int quad = lane >> 4;
    const int rbase = bx * 128 + wave * 32;

    const int sn = tid >> 1, shf = tid & 1;
    float4 stg[8];
    {
        const float4* g = (const float4*)(Wt + sn * 128 + shf * 64);
#pragma unroll
        for (int j = 0; j < 8; j++) stg[j] = g[j];
    }

    f16x8 ah[2][4], al[2][4];
#pragma unroll
    for (int rt = 0; rt < 2; rt++) {
        int r = rbase + rt * 16 + mrow;
        if (r > N - 1) r = N - 1;
        const _Float16* pa = Ahi + (size_t)r * 128 + quad * 8;
        const _Float16* pl = Alo + (size_t)r * 128 + quad * 8;
#pragma unroll
        for (int s = 0; s < 4; s++) {
            ah[rt][s] = *(const f16x8*)(pa + s * 32);
            al[rt][s] = *(const f16x8*)(pl + s * 32);
        }
    }

    {
        float4* d = (float4*)&ldsW[sn * 136 + shf * 64];
#pragma unroll
        for (int j = 0; j < 8; j++) d[j] = stg[j];
    }

    f32x4 acc[2][8];
#pragma unroll
    for (int rt = 0; rt < 2; rt++)
#pragma unroll
        for (int c = 0; c < 8; c++) acc[rt][c] = (f32x4){0.f, 0.f, 0.f, 0.f};

    __syncthreads();

#pragma unroll
    for (int s = 0; s < 4; s++) {
#pragma unroll
        for (int c = 0; c < 8; c++) {
            f16x8 bw = *(const f16x8*)&ldsW[(c * 16 + mrow) * 136 + s * 32 + quad * 8];
            acc[0][c] = __builtin_amdgcn_mfma_f32_16x16x32_f16(ah[0][s], bw, acc[0][c], 0, 0, 0);
            acc[0][c] = __builtin_amdgcn_mfma_f32_16x16x32_f16(al[0][s], bw, acc[0][c], 0, 0, 0);
            acc[1][c] = __builtin_amdgcn_mfma_f32_16x16x32_f16(ah[1][s], bw, acc[1][c], 0, 0, 0);
            acc[1][c] = __builtin_amdgcn_mfma_f32_16x16x32_f16(al[1][s], bw, acc[1][c], 0, 0, 0);
        }
    }

    // D mapping: col = lane&15, row = quad*4 + reg
#pragma unroll
    for (int rt = 0; rt < 2; rt++)
#pragma unroll
        for (int i = 0; i < 4; i++) {
            int r = rbase + rt * 16 + quad * 4 + i;
            if (r < N) {
                _Float16* cr = C + (size_t)r * 128 + mrow;
#pragma unroll
                for (int c = 0; c < 8; c++) cr[c * 16] = (_Float16)acc[rt][c][i];
            }
        }
}

// ---------------------------------------------------------------------------
// per-bucket counting sort body -> start/deg/sorted_src (src<<8 byte offsets)
// ---------------------------------------------------------------------------
__device__ __forceinline__ void sort_bucket_body(
    SharedU& L, const int2* __restrict__ staging, const int* __restrict__ gcursor,
    int* __restrict__ start, int* __restrict__ deg,
    int* __restrict__ sorted_src, int N, int b)
{
    int t = threadIdx.x;
    int r0 = b * BCAP;
    int r1 = r0 + gcursor[b];
    L.s.lhist[t] = 0;
    __syncthreads();
    for (int i = r0 + t; i < r1; i += 256) atomicAdd(&L.s.lhist[staging[i].y & 255], 1);
    __syncthreads();
    int v = L.s.lhist[t];
    L.s.lscan[t] = v;
    __syncthreads();
    for (int off = 1; off < 256; off <<= 1) {
        int u = (t >= off) ? L.s.lscan[t - off] : 0;
        __syncthreads();
        L.s.lscan[t] += u;
        __syncthreads();
    }
    int excl = L.s.lscan[t] - v;
    int node = b * NPB + t;
    if (node < N) { start[node] = r0 + excl; deg[node] = v; }
    L.s.lcur[t] = excl;
    __syncthreads();
    for (int i = r0 + t; i < r1; i += 256) {
        int2 p = staging[i];
        int rank = atomicAdd(&L.s.lcur[p.y & 255], 1);
        sorted_src[r0 + rank] = p.x << 8;
    }
}

// ---------------------------------------------------------------------------
// Fused score+softmax+aggregate: grid-stride over node pairs (2 nodes/wave,
// lockstep groups, 2-stage pipeline, byte-offset gathers, group-0 self-loop
// specialization, v_exp2 softmax, DPP reduction). No early return (grid-sync
// safe). Lanes 0-15 store node0, 16-31 node1.
// ---------------------------------------------------------------------------
template <int H, bool BFOUT>
__device__ __forceinline__ void fused_pairs_body(
    const _Float16* __restrict__ xl, const _Float16* __restrict__ xr,
    const float* __restrict__ att, const float* __restrict__ bias,
    const int* __restrict__ start, const int* __restrict__ deg,
    const int* __restrict__ sorted_src,
    float* __restrict__ outf, _Float16* __restrict__ oh,
    _Float16* __restrict__ ol, int N, int npairs)
{
    const int wid = threadIdx.x >> 6;
    const int lane = threadIdx.x & 63;
    const int g  = lane >> 4;
    const int hl = lane & 15;
    const unsigned hl16 = (unsigned)hl * 16;
    const _Float16 NS = (_Float16)NEG_SLOPE;
    const float L2E = 1.44269504f;

    float4 at0 = *(const float4*)(att + hl * 8);
    float4 at1 = *(const float4*)(att + hl * 8 + 4);
    float4 bi0 = *(const float4*)(bias + hl * 8);
    float4 bi1 = *(const float4*)(bias + hl * 8 + 4);
#if defined(HAVE_FDOT2)
    f16x2 av0 = {(_Float16)(at0.x * L2E), (_Float16)(at0.y * L2E)};
    f16x2 av1 = {(_Float16)(at0.z * L2E), (_Float16)(at0.w * L2E)};
    f16x2 av2 = {(_Float16)(at1.x * L2E), (_Float16)(at1.y * L2E)};
    f16x2 av3 = {(_Float16)(at1.z * L2E), (_Float16)(at1.w * L2E)};
#else
    f32x8 avf = {at0.x * L2E, at0.y * L2E, at0.z * L2E, at0.w * L2E,
                 at1.x * L2E, at1.y * L2E, at1.z * L2E, at1.w * L2E};
#endif

    auto score = [&](f16x8 a_, f16x8 b4_) -> float {
        f16x8 t = a_ + b4_;
        f16x8 u = __builtin_elementwise_max(t, t * NS);
#if defined(HAVE_FDOT2)
        f16x2 u0 = __builtin_shufflevector(u, u, 0, 1);
        f16x2 u1 = __builtin_shufflevector(u, u, 2, 3);
        f16x2 u2 = __builtin_shufflevector(u, u, 4, 5);
        f16x2 u3 = __builtin_shufflevector(u, u, 6, 7);
        return __builtin_amdgcn_fdot2(u0, av0,
               __builtin_amdgcn_fdot2(u1, av1,
               __builtin_amdgcn_fdot2(u2, av2,
               __builtin_amdgcn_fdot2(u3, av3, 0.f, false), false), false), false);
#else
        f32x8 uf = __builtin_convertvector(u, f32x8);
        float pp = 0.f;
#pragma unroll
        for (int i = 0; i < 8; i++) pp += uf[i] * avf[i];
        return pp;
#endif
    };

    auto red = [&](float v) -> float {
        v = dpp_add<0xB1>(v);
        v = dpp_add<0x4E>(v);
        v = dpp_add<0x141>(v);
        if (H == 1) v = dpp_add<0x140>(v);
        return v;
    };

    const unsigned cap = (unsigned)(N - 1) << 8;
    auto ldoff = [&](int pos) -> unsigned {
        unsigned v = (unsigned)sorted_src[pos];
        return (v < cap) ? v : cap;
    };
    auto grow = [&](unsigned off) -> f16x8 {
        return *(const f16x8*)((const char*)xl + (size_t)(off + hl16));
    };

    for (int p = blockIdx.x * 4 + wid; p < npairs; p += gridDim.x * 4) {
        const int n0 = 2 * p;
        const bool has1 = (n0 + 1) < N;
        const int n1 = has1 ? n0 + 1 : n0;
        const int s00 = start[n0], M0 = deg[n0] + 1;
        const int s01 = start[n1], M1 = deg[n1] + 1;

        const f16x8 b40 = *(const f16x8*)(xr + (size_t)n0 * 128 + hl * 8);
        const f16x8 b41 = *(const f16x8*)(xr + (size_t)n1 * 128 + hl * 8);

        const int Mmax = (M0 > M1) ? M0 : M1;
        const int K   = (Mmax + 3) >> 2;
        const int KK  = (K + 1) & ~1;

        f32x8 acc0 = {0.f, 0.f, 0.f, 0.f, 0.f, 0.f, 0.f, 0.f};
        f32x8 acc1 = {0.f, 0.f, 0.f, 0.f, 0.f, 0.f, 0.f, 0.f};
        float den0 = 0.f, den1 = 0.f;

        auto cone = [&](int kk, f16x8 a, f16x8 b4_, int M_, float& den_, f32x8& acc_) {
            float v = red(score(a, b4_));
            float e = (4 * kk + g < M_) ? FEXP2(v) : 0.f;
            den_ += e;
#pragma unroll
            for (int i = 0; i < 8; i++)
                acc_[i] = fmaf((float)a[i], e, acc_[i]);
        };

        unsigned o00 = (g == 0) ? (unsigned)n0 << 8 : ldoff(s00 + g - 1);
        unsigned o01 = (g == 0) ? (unsigned)n1 << 8 : ldoff(s01 + g - 1);
        unsigned o10 = ldoff(s00 + g + 3);
        unsigned o11 = ldoff(s01 + g + 3);
        f16x8 c00 = grow(o00), c01 = grow(o01), c10 = grow(o10), c11 = grow(o11);
        for (int k = 2; k < KK; k += 2) {
            unsigned p00 = ldoff(s00 + 4 * k + g - 1);
            unsigned p01 = ldoff(s01 + 4 * k + g - 1);
            unsigned p10 = ldoff(s00 + 4 * k + g + 3);
            unsigned p11 = ldoff(s01 + 4 * k + g + 3);
            f16x8 d00 = grow(p00), d01 = grow(p01), d10 = grow(p10), d11 = grow(p11);
            cone(k - 2, c00, b40, M0, den0, acc0);
            cone(k - 2, c01, b41, M1, den1, acc1);
            cone(k - 1, c10, b40, M0, den0, acc0);
            cone(k - 1, c11, b41, M1, den1, acc1);
            c00 = d00; c01 = d01; c10 = d10; c11 = d11;
        }
        cone(KK - 2, c00, b40, M0, den0, acc0);
        cone(KK - 2, c01, b41, M1, den1, acc1);
        cone(KK - 1, c10, b40, M0, den0, acc0);
        cone(KK - 1, c11, b41, M1, den1, acc1);

        den0 += __shfl_xor(den0, 16, 64);
        den0 += __shfl_xor(den0, 32, 64);
        den1 += __shfl_xor(den1, 16, 64);
        den1 += __shfl_xor(den1, 32, 64);
#pragma unroll
        for (int i = 0; i < 8; i++) {
            acc0[i] += __shfl_xor(acc0[i], 16, 64);
            acc0[i] += __shfl_xor(acc0[i], 32, 64);
            acc1[i] += __shfl_xor(acc1[i], 16, 64);
            acc1[i] += __shfl_xor(acc1[i], 32, 64);
        }

        const int which = lane >> 4;
        if (which == 0 || (which == 1 && has1)) {
            float inv = 1.0f / (which == 0 ? den0 : den1);
            int nodeo = (which == 0) ? n0 : n1;
            float o[8];
#pragma unroll
            for (int i = 0; i < 8; i++) {
                float a = (which == 0) ? acc0[i] : acc1[i];
                float b = (i < 4) ? ((i == 0) ? bi0.x : (i == 1) ? bi0.y : (i == 2) ? bi0.z : bi0.w)
                                  : ((i == 4) ? bi1.x : (i == 5) ? bi1.y : (i == 6) ? bi1.z : bi1.w);
                o[i] = a * inv + b;
            }
            if (BFOUT) {
                f16x8 hv, lv;
#pragma unroll
                for (int i = 0; i < 8; i++) {
                    _Float16 h = (_Float16)o[i];
                    hv[i] = h;
                    lv[i] = (_Float16)(o[i] - (float)h);
                }
                *(f16x8*)(oh + (size_t)nodeo * 128 + hl * 8) = hv;
                *(f16x8*)(ol + (size_t)nodeo * 128 + hl * 8) = lv;
            } else {
                *(float4*)(outf + (size_t)nodeo * 128 + hl * 8) =
                    make_float4(o[0], o[1], o[2], o[3]);
                *(float4*)(outf + (size_t)nodeo * 128 + hl * 8 + 4) =
                    make_float4(o[4], o[5], o[6], o[7]);
            }
        }
    }
}

// ---------------------------------------------------------------------------
// Cooperative mega-kernel: all 6 phases, grid.sync() between.
// ---------------------------------------------------------------------------
struct MegaArgs {
    const float *W0, *W1, *W2, *W3;
    _Float16 *wt;
    const float *x;
    _Float16 *xh, *xlo;
    int total;                 // nf
    const int *ei;
    int *gcursor;
    int2 *staging;
    int E, B0;                 // grid_chunk
    int *start, *deg, *sorted_src;
    int N, NB, gx, npairs;
    _Float16 *xlf, *xrf;
    const float *att1, *b1, *att2, *b2;
    float *out;
};

__global__ __launch_bounds__(256, 4) void mega_kernel(MegaArgs a)
{
    __shared__ SharedU lds;
    cg::grid_group grid = cg::this_grid();
    const int t = threadIdx.x;
    const int G = gridDim.x;

    // ---- Phase A: cursor zero + W transpose + x hi/lo split ----
    if (blockIdx.x == 0) a.gcursor[t] = 0;
    for (int idx = blockIdx.x * 256 + t; idx < 65536; idx += G * 256) {
        int m = idx >> 14, k = (idx >> 7) & 127, n = idx & 127;
        const float* W = (m == 0) ? a.W0 : (m == 1) ? a.W1 : (m == 2) ? a.W2 : a.W3;
        a.wt[m * 16384 + n * 128 + k] = (_Float16)W[k * 128 + n];
    }
    for (int i = blockIdx.x * 256 + t; i * 2 < a.total; i += G * 256) {
        float2 f = *(const float2*)(a.x + (size_t)i * 2);
        _Float16 h0 = (_Float16)f.x, h1 = (_Float16)f.y;
        _Float16 l0 = (_Float16)(f.x - (float)h0), l1 = (_Float16)(f.y - (float)h1);
        *(f16x2*)(a.xh  + (size_t)i * 2) = (f16x2){h0, h1};
        *(f16x2*)(a.xlo + (size_t)i * 2) = (f16x2){l0, l1};
    }
    __threadfence(); grid.sync(); __threadfence();

    // ---- Phase B: bucketing (B0 chunks) || GEMM L1 (2*gx tiles) ----
    for (int item = blockIdx.x; item < a.B0 + 2 * a.gx; item += G) {
        __syncthreads();
        if (item < a.B0) {
            bucket_chunk_body(lds, a.ei, a.gcursor, a.staging, a.E, item);
        } else {
            int gb = item - a.B0;
            int y = (gb >= a.gx) ? 1 : 0;
            gemm_body(a.xh, a.xlo, y ? a.wt + 16384 : a.wt,
                      y ? a.xrf : a.xlf, a.N, y ? gb - a.gx : gb, lds.w);
        }
    }
    __threadfence(); grid.sync(); __threadfence();

    // ---- Phase C: per-bucket counting sort ----
    for (int b = blockIdx.x; b < a.NB; b += G) {
        __syncthreads();
        sort_bucket_body(lds, a.staging, a.gcursor, a.start, a.deg,
                         a.sorted_src, a.N, b);
    }
    __threadfence(); grid.sync(); __threadfence();

    // ---- Phase D: fused layer 1 (heads=2, fp16 hi/lo out into xh/xlo) ----
    fused_pairs_body<2, true>(a.xlf, a.xrf, a.att1, a.b1, a.start, a.deg,
                              a.sorted_src, nullptr, a.xh, a.xlo, a.N, a.npairs);
    __threadfence(); grid.sync(); __threadfence();

    // ---- Phase E: GEMM L2 ----
    for (int item = blockIdx.x; item < 2 * a.gx; item += G) {
        __syncthreads();
        int y = (item >= a.gx) ? 1 : 0;
        gemm_body(a.xh, a.xlo, y ? a.wt + 3 * 16384 : a.wt + 2 * 16384,
                  y ? a.xrf : a.xlf, a.N, y ? item - a.gx : item, lds.w);
    }
    __threadfence(); grid.sync(); __threadfence();

    // ---- Phase F: fused layer 2 (heads=1, fp32 out) ----
    fused_pairs_body<1, false>(a.xlf, a.xrf, a.att2, a.b2, a.start, a.deg,
                               a.sorted_src, a.out, nullptr, nullptr, a.N, a.npairs);
}

// ---------------------------------------------------------------------------
// Fallback multi-launch kernels (r8 structure) reusing the same bodies.
// ---------------------------------------------------------------------------
__global__ __launch_bounds__(256) void k1_prep_bucket_kernel(
    const float* __restrict__ W0, const float* __restrict__ W1,
    const float* __restrict__ W2, const float* __restrict__ W3,
    _Float16* __restrict__ wt,
    const float* __restrict__ x, _Float16* __restrict__ xh,
    _Float16* __restrict__ xlo, int total,
    const int* __restrict__ ei, int* __restrict__ gcursor,
    int2* __restrict__ staging, int E, int B0)
{
    __shared__ SharedU lds;
    int t = threadIdx.x;
    int bid = blockIdx.x;
    if (bid < B0) {
        bucket_chunk_body(lds, ei, gcursor, staging, E, bid);
    } else if (bid < B0 + 256) {
        int idx = (bid - B0) * 256 + t;
        int m = idx >> 14, k = (idx >> 7) & 127, n = idx & 127;
        const float* W = (m == 0) ? W0 : (m == 1) ? W1 : (m == 2) ? W2 : W3;
        wt[m * 16384 + n * 128 + k] = (_Float16)W[k * 128 + n];
    } else {
        int i = (bid - B0 - 256) * 256 + t;
        if (i * 2 < total) {
            float2 f = *(const float2*)(x + (size_t)i * 2);
            _Float16 h0 = (_Float16)f.x, h1 = (_Float16)f.y;
            _Float16 l0 = (_Float16)(f.x - (float)h0), l1 = (_Float16)(f.y - (float)h1);
            *(f16x2*)(xh  + (size_t)i * 2) = (f16x2){h0, h1};
            *(f16x2*)(xlo + (size_t)i * 2) = (f16x2){l0, l1};
        }
    }
}

__global__ __launch_bounds__(256) void k2_sort_gemm_kernel(
    const int2* __restrict__ staging, const int* __restrict__ gcursor,
    int* __restrict__ start, int* __restrict__ deg,
    int* __restrict__ sorted_src, int N, int NBv,
    const _Float16* __restrict__ Ahi, const _Float16* __restrict__ Alo,
    const _Float16* __restrict__ Wt0, const _Float16* __restrict__ Wt1,
    _Float16* __restrict__ Cl, _Float16* __restrict__ Cr, int gx)
{
    __shared__ SharedU lds;
    int bx = blockIdx.x;
    if (bx < NBv) {
        sort_bucket_body(lds, staging, gcursor, start, deg, sorted_src, N, bx);
    } else {
        int gb = bx - NBv;
        int y = (gb >= gx) ? 1 : 0;
        gemm_body(Ahi, Alo, y ? Wt1 : Wt0, y ? Cr : Cl, N, y ? gb - gx : gb, lds.w);
    }
}

__global__ __launch_bounds__(256) void gemm_f16_kernel(
    const _Float16* __restrict__ Ahi, const _Float16* __restrict__ Alo,
    const _Float16* __restrict__ Wt0, const _Float16* __restrict__ Wt1,
    _Float16* __restrict__ Cl, _Float16* __restrict__ Cr, int N)
{
    __shared__ SharedU lds;
    gemm_body(Ahi, Alo, blockIdx.y ? Wt1 : Wt0, blockIdx.y ? Cr : Cl, N,
              blockIdx.x, lds.w);
}

template <int H, bool BFOUT>
__global__ __launch_bounds__(256) void gat_fused_kernel(
    const _Float16* __restrict__ xl, const _Float16* __restrict__ xr,
    const float* __restrict__ att, const float* __restrict__ bias,
    const int* __restrict__ start, const int* __restrict__ deg,
    const int* __restrict__ sorted_src,
    float* __restrict__ outf, _Float16* __restrict__ oh,
    _Float16* __restrict__ ol, int N, int npairs)
{
    fused_pairs_body<H, BFOUT>(xl, xr, att, bias, start, deg, sorted_src,
                               outf, oh, ol, N, npairs);
}

// ---------------------------------------------------------------------------
extern "C" void kernel_launch(void* const* d_in, const int* in_sizes, int n_in,
                              void* d_out, int out_size, void* d_ws, size_t ws_size,
                              hipStream_t stream)
{
    const float* x    = (const float*)d_in[0];
    const int*   ei   = (const int*)d_in[1];
    const float* Wl1  = (const float*)d_in[3];
    const float* Wr1  = (const float*)d_in[4];
    const float* att1 = (const float*)d_in[5];
    const float* b1   = (const float*)d_in[6];
    const float* Wl2  = (const float*)d_in[7];
    const float* Wr2  = (const float*)d_in[8];
    const float* att2 = (const float*)d_in[9];
    const float* b2   = (const float*)d_in[10];
    float* out = (float*)d_out;

    const int N  = in_sizes[0] / 128;
    const int E  = in_sizes[1] / 2;
    const int NB = (N + NPB - 1) / NPB;

    const size_t nf = (size_t)N * 128;
    _Float16* xlf  = (_Float16*)d_ws;
    _Float16* xrf  = xlf + nf;
    _Float16* ah   = xrf + nf;
    _Float16* al   = ah + nf;
    _Float16* wt   = al + nf;
    int* gcursor   = (int*)(wt + 4 * 16384);
    int* start     = gcursor + 256;
    int* deg       = start + N;
    size_t stgoff  = ((size_t)(deg + N) + 7) & ~(size_t)7;
    int2* staging  = (int2*)stgoff;
    int* sorted_src = (int*)(staging + (size_t)NB * BCAP);

    const int grid_chunk = (E + CHUNK - 1) / CHUNK;
    const int npairs     = (N + 1) / 2;
    const int gemm_gx    = (N + 127) / 128;
    const int split_grid = (int)((nf / 2 + 255) / 256);

    // one-time: query cooperative capacity
    static int s_coop = -1;
    static int s_grid = 0;
    if (s_coop < 0) {
        int dev = 0;
        hipGetDevice(&dev);
        hipDeviceProp_t prop;
        int maxb = 0;
        if (hipGetDeviceProperties(&prop, dev) == hipSuccess &&
            hipOccupancyMaxActiveBlocksPerMultiprocessor(
                &maxb, (const void*)mega_kernel, 256, 0) == hipSuccess &&
            maxb > 0 && prop.cooperativeLaunch) {
            s_grid = maxb * prop.multiProcessorCount;
            s_coop = 1;
        } else {
            s_coop = 0;
        }
    }

    if (s_coop == 1) {
        MegaArgs a;
        a.W0 = Wl1; a.W1 = Wr1; a.W2 = Wl2; a.W3 = Wr2;
        a.wt = wt; a.x = x; a.xh = ah; a.xlo = al; a.total = (int)nf;
        a.ei = ei; a.gcursor = gcursor; a.staging = staging;
        a.E = E; a.B0 = grid_chunk;
        a.start = start; a.deg = deg; a.sorted_src = sorted_src;
        a.N = N; a.NB = NB; a.gx = gemm_gx; a.npairs = npairs;
        a.xlf = xlf; a.xrf = xrf;
        a.att1 = att1; a.b1 = b1; a.att2 = att2; a.b2 = b2;
        a.out = out;
        void* params[] = { &a };
        hipError_t err = hipLaunchCooperativeKernel(
            (const void*)mega_kernel, dim3(s_grid), dim3(256), params, 0, stream);
        if (err == hipSuccess) return;
        s_coop = 0;   // fall through to multi-launch
    }

    // ---- fallback: r8 multi-launch pipeline ----
    int node_grid = (npairs + 3) / 4;
    if (node_grid > 2048) node_grid = 2048;

    hipMemsetAsync(gcursor, 0, 256 * sizeof(int), stream);
    k1_prep_bucket_kernel<<<grid_chunk + 256 + split_grid, 256, 0, stream>>>(
        Wl1, Wr1, Wl2, Wr2, wt, x, ah, al, (int)nf,
        ei, gcursor, staging, E, grid_chunk);
    k2_sort_gemm_kernel<<<NB + 2 * gemm_gx, 256, 0, stream>>>(
        staging, gcursor, start, deg, sorted_src, N, NB,
        ah, al, wt + 0 * 16384, wt + 1 * 16384, xlf, xrf, gemm_gx);
    gat_fused_kernel<2, true><<<node_grid, 256, 0, stream>>>(
        xlf, xrf, att1, b1, start, deg, sorted_src, nullptr, ah, al, N, npairs);
    gemm_f16_kernel<<<dim3(gemm_gx, 2), 256, 0, stream>>>(
        ah, al, wt + 2 * 16384, wt + 3 * 16384, xlf, xrf, N);
    gat_fused_kernel<1, false><<<node_grid, 256, 0, stream>>>(
        xlf, xrf, att2, b2, start, deg, sorted_src, out, nullptr, nullptr, N, npairs);
}

// Round 11
// 282.096 us; speedup vs baseline: 3.7442x; 3.7442x over previous
//
#include <hip/hip_runtime.h>

#define NEG_SLOPE 0.2f
#define NPB 256          // nodes per dst-bucket (bucket = dst >> 8)
#define CHUNK 4096       // edges per partition block
#define BCAP 5120        // padded bucket capacity (expected fill 4096, +16 sigma)

typedef _Float16 f16x8 __attribute__((ext_vector_type(8)));
typedef _Float16 f16x4 __attribute__((ext_vector_type(4)));
typedef _Float16 f16x2 __attribute__((ext_vector_type(2)));
typedef float    f32x4 __attribute__((ext_vector_type(4)));
typedef float    f32x8 __attribute__((ext_vector_type(8)));

#if defined(__has_builtin)
#if __has_builtin(__builtin_amdgcn_fdot2)
#define HAVE_FDOT2 1
#endif
#if __has_builtin(__builtin_amdgcn_exp2f)
#define FEXP2(x) __builtin_amdgcn_exp2f(x)
#endif
#endif
#ifndef FEXP2
#define FEXP2(x) exp2f(x)
#endif

// DPP butterfly add — pure VALU. 0xB1=xor1, 0x4E=xor2, 0x141=xor4(half-mirror
// once quads uniform), 0x140=xor8(mirror once 8-groups uniform).
template <int CTRL>
__device__ __forceinline__ float dpp_add(float v) {
    int o = __builtin_amdgcn_update_dpp(0, __builtin_bit_cast(int, v),
                                        CTRL, 0xF, 0xF, true);
    return v + __builtin_bit_cast(float, o);
}

// Shared-memory union across phase bodies (36,864 B -> 4 blocks/CU by LDS).
union SharedU {
    struct { int2 pairs[CHUNK]; int bh[256]; int bbase[256]; int exb[256]; int scn[256]; } b;
    _Float16 w[128 * 136];
    struct { int lhist[256]; int lscan[256]; int lcur[256]; } s;
};

// ---------------------------------------------------------------------------
// chunk bucketing body (LDS counting-sort -> coalesced per-bucket flush)
// ---------------------------------------------------------------------------
__device__ __forceinline__ void bucket_chunk_body(
    SharedU& L, const int* __restrict__ ei, int* __restrict__ gcursor,
    int2* __restrict__ staging, int E, int bid)
{
    int t = threadIdx.x;
    L.b.bh[t] = 0;
    __syncthreads();
    int base = bid * CHUNK;
    int srcv[16], dstv[16], rb[16];
#pragma unroll
    for (int j = 0; j < 16; j++) {
        int e = base + t + j * 256;
        if (e < E) {
            int d = ei[E + e];
            srcv[j] = ei[e];
            dstv[j] = d;
            int bk = d >> 8;
            int r = atomicAdd(&L.b.bh[bk], 1);
            rb[j] = (r << 8) | bk;
        } else rb[j] = -1;
    }
    __syncthreads();
    int v = L.b.bh[t];
    L.b.scn[t] = v;
    __syncthreads();
    for (int off = 1; off < 256; off <<= 1) {
        int u = (t >= off) ? L.b.scn[t - off] : 0;
        __syncthreads();
        L.b.scn[t] += u;
        __syncthreads();
    }
    int ex = L.b.scn[t] - v;
    int tot = L.b.scn[255];
    L.b.exb[t] = ex;
    if (v) L.b.bbase[t] = t * BCAP + atomicAdd(&gcursor[t], v);
    __syncthreads();
#pragma unroll
    for (int j = 0; j < 16; j++) {
        if (rb[j] >= 0) {
            int bk = rb[j] & 255, r = rb[j] >> 8;
            L.b.pairs[L.b.exb[bk] + r] = make_int2(srcv[j], dstv[j]);
        }
    }
    __syncthreads();
    for (int i = t; i < tot; i += 256) {
        int2 p = L.b.pairs[i];
        int bk = p.y >> 8;
        staging[L.b.bbase[bk] + (i - L.b.exb[bk])] = p;
    }
}

// ---------------------------------------------------------------------------
// fp16 MFMA GEMM, TWO tiles per block: all loads (W + A0 + A1) issued before
// the single barrier; W stays resident in LDS for both tiles; no further
// syncs. Doubles per-block ILP vs the one-shot body and halves W-staging +
// barrier count (round-9 latency theory for the invisible mid kernels).
// C = Ah@W + Al@W, fp32 acc. t1 = -1 if the block has only one tile.
// ---------------------------------------------------------------------------
__device__ __forceinline__ void gemm_tiles_body(
    const _Float16* __restrict__ Ahi, const _Float16* __restrict__ Alo,
    const _Float16* __restrict__ Wt, _Float16* __restrict__ C, int N,
    int t0, int t1, _Float16* ldsW)
{
    const int tid = threadIdx.x;
    const int wave = tid >> 6;
    const int lane = tid & 63;
    const int mrow = lane & 15;
    const int quad = lane >> 4;
    const int sn = tid >> 1, shf = tid & 1;

    // W staging loads first
    float4 stg[8];
    {
        const float4* g = (const float4*)(Wt + sn * 128 + shf * 64);
#pragma unroll
        for (int j = 0; j < 8; j++) stg[j] = g[j];
    }

    auto load_tile = [&](int bx, f16x8 (&ah)[2][4], f16x8 (&al)[2][4]) {
        const int rbase = bx * 128 + wave * 32;
#pragma unroll
        for (int rt = 0; rt < 2; rt++) {
            int r = rbase + rt * 16 + mrow;
            if (r > N - 1) r = N - 1;
            const _Float16* pa = Ahi + (size_t)r * 128 + quad * 8;
            const _Float16* pl = Alo + (size_t)r * 128 + quad * 8;
#pragma unroll
            for (int s = 0; s < 4; s++) {
                ah[rt][s] = *(const f16x8*)(pa + s * 32);
                al[rt][s] = *(const f16x8*)(pl + s * 32);
            }
        }
    };

    f16x8 a0h[2][4], a0l[2][4], a1h[2][4], a1l[2][4];
    load_tile(t0, a0h, a0l);
    if (t1 >= 0) load_tile(t1, a1h, a1l);

    {
        float4* d = (float4*)&ldsW[sn * 136 + shf * 64];
#pragma unroll
        for (int j = 0; j < 8; j++) d[j] = stg[j];
    }
    __syncthreads();

    auto compute_store = [&](int bx, f16x8 (&ah)[2][4], f16x8 (&al)[2][4]) {
        const int rbase = bx * 128 + wave * 32;
        f32x4 acc[2][8];
#pragma unroll
        for (int rt = 0; rt < 2; rt++)
#pragma unroll
            for (int c = 0; c < 8; c++) acc[rt][c] = (f32x4){0.f, 0.f, 0.f, 0.f};

#pragma unroll
        for (int s = 0; s < 4; s++) {
#pragma unroll
            for (int c = 0; c < 8; c++) {
                f16x8 bw = *(const f16x8*)&ldsW[(c * 16 + mrow) * 136 + s * 32 + quad * 8];
                acc[0][c] = __builtin_amdgcn_mfma_f32_16x16x32_f16(ah[0][s], bw, acc[0][c], 0, 0, 0);
                acc[0][c] = __builtin_amdgcn_mfma_f32_16x16x32_f16(al[0][s], bw, acc[0][c], 0, 0, 0);
                acc[1][c] = __builtin_amdgcn_mfma_f32_16x16x32_f16(ah[1][s], bw, acc[1][c], 0, 0, 0);
                acc[1][c] = __builtin_amdgcn_mfma_f32_16x16x32_f16(al[1][s], bw, acc[1][c], 0, 0, 0);
            }
        }

        // D mapping: col = lane&15, row = quad*4 + reg
#pragma unroll
        for (int rt = 0; rt < 2; rt++)
#pragma unroll
            for (int i = 0; i < 4; i++) {
                int r = rbase + rt * 16 + quad * 4 + i;
                if (r < N) {
                    _Float16* cr = C + (size_t)r * 128 + mrow;
#pragma unroll
                    for (int c = 0; c < 8; c++) cr[c * 16] = (_Float16)acc[rt][c][i];
                }
            }
    };

    compute_store(t0, a0h, a0l);
    if (t1 >= 0) compute_store(t1, a1h, a1l);
}

// ---------------------------------------------------------------------------
// per-bucket counting sort body -> start/deg/sorted_src (src<<8 byte offsets)
// ---------------------------------------------------------------------------
__device__ __forceinline__ void sort_bucket_body(
    SharedU& L, const int2* __restrict__ staging, const int* __restrict__ gcursor,
    int* __restrict__ start, int* __restrict__ deg,
    int* __restrict__ sorted_src, int N, int b)
{
    int t = threadIdx.x;
    int r0 = b * BCAP;
    int r1 = r0 + gcursor[b];
    L.s.lhist[t] = 0;
    __syncthreads();
    for (int i = r0 + t; i < r1; i += 256) atomicAdd(&L.s.lhist[staging[i].y & 255], 1);
    __syncthreads();
    int v = L.s.lhist[t];
    L.s.lscan[t] = v;
    __syncthreads();
    for (int off = 1; off < 256; off <<= 1) {
        int u = (t >= off) ? L.s.lscan[t - off] : 0;
        __syncthreads();
        L.s.lscan[t] += u;
        __syncthreads();
    }
    int excl = L.s.lscan[t] - v;
    int node = b * NPB + t;
    if (node < N) { start[node] = r0 + excl; deg[node] = v; }
    L.s.lcur[t] = excl;
    __syncthreads();
    for (int i = r0 + t; i < r1; i += 256) {
        int2 p = staging[i];
        int rank = atomicAdd(&L.s.lcur[p.y & 255], 1);
        sorted_src[r0 + rank] = p.x << 8;
    }
}

// ---------------------------------------------------------------------------
// Fused score+softmax+aggregate: grid-stride over node pairs (2 nodes/wave,
// lockstep groups, 2-stage pipeline, byte-offset gathers, group-0 self-loop
// specialization, v_exp2 softmax, DPP reduction).
// ---------------------------------------------------------------------------
template <int H, bool BFOUT>
__device__ __forceinline__ void fused_pairs_body(
    const _Float16* __restrict__ xl, const _Float16* __restrict__ xr,
    const float* __restrict__ att, const float* __restrict__ bias,
    const int* __restrict__ start, const int* __restrict__ deg,
    const int* __restrict__ sorted_src,
    float* __restrict__ outf, _Float16* __restrict__ oh,
    _Float16* __restrict__ ol, int N, int npairs)
{
    const int wid = threadIdx.x >> 6;
    const int lane = threadIdx.x & 63;
    const int g  = lane >> 4;
    const int hl = lane & 15;
    const unsigned hl16 = (unsigned)hl * 16;
    const _Float16 NS = (_Float16)NEG_SLOPE;
    const float L2E = 1.44269504f;

    float4 at0 = *(const float4*)(att + hl * 8);
    float4 at1 = *(const float4*)(att + hl * 8 + 4);
    float4 bi0 = *(const float4*)(bias + hl * 8);
    float4 bi1 = *(const float4*)(bias + hl * 8 + 4);
#if defined(HAVE_FDOT2)
    f16x2 av0 = {(_Float16)(at0.x * L2E), (_Float16)(at0.y * L2E)};
    f16x2 av1 = {(_Float16)(at0.z * L2E), (_Float16)(at0.w * L2E)};
    f16x2 av2 = {(_Float16)(at1.x * L2E), (_Float16)(at1.y * L2E)};
    f16x2 av3 = {(_Float16)(at1.z * L2E), (_Float16)(at1.w * L2E)};
#else
    f32x8 avf = {at0.x * L2E, at0.y * L2E, at0.z * L2E, at0.w * L2E,
                 at1.x * L2E, at1.y * L2E, at1.z * L2E, at1.w * L2E};
#endif

    auto score = [&](f16x8 a_, f16x8 b4_) -> float {
        f16x8 t = a_ + b4_;
        f16x8 u = __builtin_elementwise_max(t, t * NS);
#if defined(HAVE_FDOT2)
        f16x2 u0 = __builtin_shufflevector(u, u, 0, 1);
        f16x2 u1 = __builtin_shufflevector(u, u, 2, 3);
        f16x2 u2 = __builtin_shufflevector(u, u, 4, 5);
        f16x2 u3 = __builtin_shufflevector(u, u, 6, 7);
        return __builtin_amdgcn_fdot2(u0, av0,
               __builtin_amdgcn_fdot2(u1, av1,
               __builtin_amdgcn_fdot2(u2, av2,
               __builtin_amdgcn_fdot2(u3, av3, 0.f, false), false), false), false);
#else
        f32x8 uf = __builtin_convertvector(u, f32x8);
        float pp = 0.f;
#pragma unroll
        for (int i = 0; i < 8; i++) pp += uf[i] * avf[i];
        return pp;
#endif
    };

    auto red = [&](float v) -> float {
        v = dpp_add<0xB1>(v);
        v = dpp_add<0x4E>(v);
        v = dpp_add<0x141>(v);
        if (H == 1) v = dpp_add<0x140>(v);
        return v;
    };

    const unsigned cap = (unsigned)(N - 1) << 8;
    auto ldoff = [&](int pos) -> unsigned {
        unsigned v = (unsigned)sorted_src[pos];
        return (v < cap) ? v : cap;
    };
    auto grow = [&](unsigned off) -> f16x8 {
        return *(const f16x8*)((const char*)xl + (size_t)(off + hl16));
    };

    for (int p = blockIdx.x * 4 + wid; p < npairs; p += gridDim.x * 4) {
        const int n0 = 2 * p;
        const bool has1 = (n0 + 1) < N;
        const int n1 = has1 ? n0 + 1 : n0;
        const int s00 = start[n0], M0 = deg[n0] + 1;
        const int s01 = start[n1], M1 = deg[n1] + 1;

        const f16x8 b40 = *(const f16x8*)(xr + (size_t)n0 * 128 + hl * 8);
        const f16x8 b41 = *(const f16x8*)(xr + (size_t)n1 * 128 + hl * 8);

        const int Mmax = (M0 > M1) ? M0 : M1;
        const int K   = (Mmax + 3) >> 2;
        const int KK  = (K + 1) & ~1;

        f32x8 acc0 = {0.f, 0.f, 0.f, 0.f, 0.f, 0.f, 0.f, 0.f};
        f32x8 acc1 = {0.f, 0.f, 0.f, 0.f, 0.f, 0.f, 0.f, 0.f};
        float den0 = 0.f, den1 = 0.f;

        auto cone = [&](int kk, f16x8 a, f16x8 b4_, int M_, float& den_, f32x8& acc_) {
            float v = red(score(a, b4_));
            float e = (4 * kk + g < M_) ? FEXP2(v) : 0.f;
            den_ += e;
#pragma unroll
            for (int i = 0; i < 8; i++)
                acc_[i] = fmaf((float)a[i], e, acc_[i]);
        };

        unsigned o00 = (g == 0) ? (unsigned)n0 << 8 : ldoff(s00 + g - 1);
        unsigned o01 = (g == 0) ? (unsigned)n1 << 8 : ldoff(s01 + g - 1);
        unsigned o10 = ldoff(s00 + g + 3);
        unsigned o11 = ldoff(s01 + g + 3);
        f16x8 c00 = grow(o00), c01 = grow(o01), c10 = grow(o10), c11 = grow(o11);
        for (int k = 2; k < KK; k += 2) {
            unsigned p00 = ldoff(s00 + 4 * k + g - 1);
            unsigned p01 = ldoff(s01 + 4 * k + g - 1);
            unsigned p10 = ldoff(s00 + 4 * k + g + 3);
            unsigned p11 = ldoff(s01 + 4 * k + g + 3);
            f16x8 d00 = grow(p00), d01 = grow(p01), d10 = grow(p10), d11 = grow(p11);
            cone(k - 2, c00, b40, M0, den0, acc0);
            cone(k - 2, c01, b41, M1, den1, acc1);
            cone(k - 1, c10, b40, M0, den0, acc0);
            cone(k - 1, c11, b41, M1, den1, acc1);
            c00 = d00; c01 = d01; c10 = d10; c11 = d11;
        }
        cone(KK - 2, c00, b40, M0, den0, acc0);
        cone(KK - 2, c01, b41, M1, den1, acc1);
        cone(KK - 1, c10, b40, M0, den0, acc0);
        cone(KK - 1, c11, b41, M1, den1, acc1);

        den0 += __shfl_xor(den0, 16, 64);
        den0 += __shfl_xor(den0, 32, 64);
        den1 += __shfl_xor(den1, 16, 64);
        den1 += __shfl_xor(den1, 32, 64);
#pragma unroll
        for (int i = 0; i < 8; i++) {
            acc0[i] += __shfl_xor(acc0[i], 16, 64);
            acc0[i] += __shfl_xor(acc0[i], 32, 64);
            acc1[i] += __shfl_xor(acc1[i], 16, 64);
            acc1[i] += __shfl_xor(acc1[i], 32, 64);
        }

        const int which = lane >> 4;
        if (which == 0 || (which == 1 && has1)) {
            float inv = 1.0f / (which == 0 ? den0 : den1);
            int nodeo = (which == 0) ? n0 : n1;
            float o[8];
#pragma unroll
            for (int i = 0; i < 8; i++) {
                float a = (which == 0) ? acc0[i] : acc1[i];
                float b = (i < 4) ? ((i == 0) ? bi0.x : (i == 1) ? bi0.y : (i == 2) ? bi0.z : bi0.w)
                                  : ((i == 4) ? bi1.x : (i == 5) ? bi1.y : (i == 6) ? bi1.z : bi1.w);
                o[i] = a * inv + b;
            }
            if (BFOUT) {
                f16x8 hv, lv;
#pragma unroll
                for (int i = 0; i < 8; i++) {
                    _Float16 h = (_Float16)o[i];
                    hv[i] = h;
                    lv[i] = (_Float16)(o[i] - (float)h);
                }
                *(f16x8*)(oh + (size_t)nodeo * 128 + hl * 8) = hv;
                *(f16x8*)(ol + (size_t)nodeo * 128 + hl * 8) = lv;
            } else {
                *(float4*)(outf + (size_t)nodeo * 128 + hl * 8) =
                    make_float4(o[0], o[1], o[2], o[3]);
                *(float4*)(outf + (size_t)nodeo * 128 + hl * 8 + 4) =
                    make_float4(o[4], o[5], o[6], o[7]);
            }
        }
    }
}

// ---------------------------------------------------------------------------
// K1: merged prep + bucketing.
// ---------------------------------------------------------------------------
__global__ __launch_bounds__(256) void k1_prep_bucket_kernel(
    const float* __restrict__ W0, const float* __restrict__ W1,
    const float* __restrict__ W2, const float* __restrict__ W3,
    _Float16* __restrict__ wt,
    const float* __restrict__ x, _Float16* __restrict__ xh,
    _Float16* __restrict__ xlo, int total,
    const int* __restrict__ ei, int* __restrict__ gcursor,
    int2* __restrict__ staging, int E, int B0)
{
    __shared__ SharedU lds;
    int t = threadIdx.x;
    int bid = blockIdx.x;
    if (bid < B0) {
        bucket_chunk_body(lds, ei, gcursor, staging, E, bid);
    } else if (bid < B0 + 256) {
        int idx = (bid - B0) * 256 + t;
        int m = idx >> 14, k = (idx >> 7) & 127, n = idx & 127;
        const float* W = (m == 0) ? W0 : (m == 1) ? W1 : (m == 2) ? W2 : W3;
        wt[m * 16384 + n * 128 + k] = (_Float16)W[k * 128 + n];
    } else {
        // x -> fp16 hi/lo split, float4-vectorized (G13)
        int i = (bid - B0 - 256) * 256 + t;
        if (i * 4 < total) {
            float4 f = *(const float4*)(x + (size_t)i * 4);
            _Float16 h0 = (_Float16)f.x, h1 = (_Float16)f.y;
            _Float16 h2 = (_Float16)f.z, h3 = (_Float16)f.w;
            f16x4 hv = {h0, h1, h2, h3};
            f16x4 lv = {(_Float16)(f.x - (float)h0), (_Float16)(f.y - (float)h1),
                        (_Float16)(f.z - (float)h2), (_Float16)(f.w - (float)h3)};
            *(f16x4*)(xh  + (size_t)i * 4) = hv;
            *(f16x4*)(xlo + (size_t)i * 4) = lv;
        }
    }
}

// ---------------------------------------------------------------------------
// K2: merged per-bucket counting sort + layer-1 GEMM (2 tiles/block).
//   blocks [0, NB)            : counting sort -> start/deg/sorted_src
//   blocks [NB, NB+gxp)       : gemm y=0, tiles {2j, 2j+1}
//   blocks [NB+gxp, NB+2*gxp) : gemm y=1, tiles {2j, 2j+1}
// ---------------------------------------------------------------------------
__global__ __launch_bounds__(256, 2) void k2_sort_gemm_kernel(
    const int2* __restrict__ staging, const int* __restrict__ gcursor,
    int* __restrict__ start, int* __restrict__ deg,
    int* __restrict__ sorted_src, int N, int NBv,
    const _Float16* __restrict__ Ahi, const _Float16* __restrict__ Alo,
    const _Float16* __restrict__ Wt0, const _Float16* __restrict__ Wt1,
    _Float16* __restrict__ Cl, _Float16* __restrict__ Cr, int gx, int gxp)
{
    __shared__ SharedU lds;
    int bx = blockIdx.x;
    if (bx < NBv) {
        sort_bucket_body(lds, staging, gcursor, start, deg, sorted_src, N, bx);
    } else {
        int gb = bx - NBv;
        int y = (gb >= gxp) ? 1 : 0;
        int j = y ? gb - gxp : gb;
        int t0 = 2 * j;
        int t1 = (2 * j + 1 < gx) ? 2 * j + 1 : -1;
        gemm_tiles_body(Ahi, Alo, y ? Wt1 : Wt0, y ? Cr : Cl, N, t0, t1, lds.w);
    }
}

// standalone GEMM (layer 2): blockIdx.y selects W/output, 2 tiles/block
__global__ __launch_bounds__(256, 2) void gemm_f16_kernel(
    const _Float16* __restrict__ Ahi, const _Float16* __restrict__ Alo,
    const _Float16* __restrict__ Wt0, const _Float16* __restrict__ Wt1,
    _Float16* __restrict__ Cl, _Float16* __restrict__ Cr, int N, int gx)
{
    __shared__ SharedU lds;
    int t0 = 2 * blockIdx.x;
    int t1 = (t0 + 1 < gx) ? t0 + 1 : -1;
    gemm_tiles_body(Ahi, Alo, blockIdx.y ? Wt1 : Wt0, blockIdx.y ? Cr : Cl,
                    N, t0, t1, lds.w);
}

template <int H, bool BFOUT>
__global__ __launch_bounds__(256) void gat_fused_kernel(
    const _Float16* __restrict__ xl, const _Float16* __restrict__ xr,
    const float* __restrict__ att, const float* __restrict__ bias,
    const int* __restrict__ start, const int* __restrict__ deg,
    const int* __restrict__ sorted_src,
    float* __restrict__ outf, _Float16* __restrict__ oh,
    _Float16* __restrict__ ol, int N, int npairs)
{
    fused_pairs_body<H, BFOUT>(xl, xr, att, bias, start, deg, sorted_src,
                               outf, oh, ol, N, npairs);
}

// ---------------------------------------------------------------------------
extern "C" void kernel_launch(void* const* d_in, const int* in_sizes, int n_in,
                              void* d_out, int out_size, void* d_ws, size_t ws_size,
                              hipStream_t stream)
{
    const float* x    = (const float*)d_in[0];
    const int*   ei   = (const int*)d_in[1];
    const float* Wl1  = (const float*)d_in[3];
    const float* Wr1  = (const float*)d_in[4];
    const float* att1 = (const float*)d_in[5];
    const float* b1   = (const float*)d_in[6];
    const float* Wl2  = (const float*)d_in[7];
    const float* Wr2  = (const float*)d_in[8];
    const float* att2 = (const float*)d_in[9];
    const float* b2   = (const float*)d_in[10];
    float* out = (float*)d_out;

    const int N  = in_sizes[0] / 128;
    const int E  = in_sizes[1] / 2;
    const int NB = (N + NPB - 1) / NPB;

    const size_t nf = (size_t)N * 128;
    _Float16* xlf  = (_Float16*)d_ws;
    _Float16* xrf  = xlf + nf;
    _Float16* ah   = xrf + nf;
    _Float16* al   = ah + nf;
    _Float16* wt   = al + nf;
    int* gcursor   = (int*)(wt + 4 * 16384);
    int* start     = gcursor + 256;
    int* deg       = start + N;
    size_t stgoff  = ((size_t)(deg + N) + 7) & ~(size_t)7;
    int2* staging  = (int2*)stgoff;
    int* sorted_src = (int*)(staging + (size_t)NB * BCAP);

    const int grid_chunk = (E + CHUNK - 1) / CHUNK;
    const int npairs     = (N + 1) / 2;
    const int gemm_gx    = (N + 127) / 128;
    const int gemm_gxp   = (gemm_gx + 1) / 2;         // 2 tiles per block
    const int split_grid = (int)((nf / 4 + 255) / 256);

    int node_grid = (npairs + 3) / 4;
    if (node_grid > 2048) node_grid = 2048;           // persistent grid-stride

    // ---- zero bucket cursors ----
    hipMemsetAsync(gcursor, 0, 256 * sizeof(int), stream);

    // ---- K1: prep (W fp16-transpose, x hi/lo split) + chunk bucketing ----
    k1_prep_bucket_kernel<<<grid_chunk + 256 + split_grid, 256, 0, stream>>>(
        Wl1, Wr1, Wl2, Wr2, wt, x, ah, al, (int)nf,
        ei, gcursor, staging, E, grid_chunk);

    // ---- K2: per-bucket counting sort + layer-1 GEMM (both halves) ----
    k2_sort_gemm_kernel<<<NB + 2 * gemm_gxp, 256, 0, stream>>>(
        staging, gcursor, start, deg, sorted_src, N, NB,
        ah, al, wt + 0 * 16384, wt + 1 * 16384, xlf, xrf, gemm_gx, gemm_gxp);

    // ---- Layer 1 fused ----
    gat_fused_kernel<2, true><<<node_grid, 256, 0, stream>>>(
        xlf, xrf, att1, b1, start, deg, sorted_src, nullptr, ah, al, N, npairs);

    // ---- Layer 2: GEMM + fused ----
    gemm_f16_kernel<<<dim3(gemm_gxp, 2), 256, 0, stream>>>(
        ah, al, wt + 2 * 16384, wt + 3 * 16384, xlf, xrf, N, gemm_gx);
    gat_fused_kernel<1, false><<<node_grid, 256, 0, stream>>>(
        xlf, xrf, att2, b2, start, deg, sorted_src, out, nullptr, nullptr, N, npairs);
}

// Round 12
// 266.632 us; speedup vs baseline: 3.9613x; 1.0580x over previous
//
#include <hip/hip_runtime.h>

#define NEG_SLOPE 0.2f
#define NPB 256          // nodes per dst-bucket (bucket = dst >> 8)
#define CHUNK 4096       // edges per partition block
#define BCAP 5120        // padded bucket capacity (expected fill 4096, +16 sigma)

typedef _Float16 f16x8 __attribute__((ext_vector_type(8)));
typedef _Float16 f16x4 __attribute__((ext_vector_type(4)));
typedef _Float16 f16x2 __attribute__((ext_vector_type(2)));
typedef float    f32x4 __attribute__((ext_vector_type(4)));
typedef float    f32x8 __attribute__((ext_vector_type(8)));

#if defined(__has_builtin)
#if __has_builtin(__builtin_amdgcn_fdot2)
#define HAVE_FDOT2 1
#endif
#if __has_builtin(__builtin_amdgcn_exp2f)
#define FEXP2(x) __builtin_amdgcn_exp2f(x)
#endif
#endif
#ifndef FEXP2
#define FEXP2(x) exp2f(x)
#endif

// DPP butterfly add — pure VALU. 0xB1=xor1, 0x4E=xor2, 0x141=xor4(half-mirror
// once quads uniform), 0x140=xor8(mirror once 8-groups uniform).
template <int CTRL>
__device__ __forceinline__ float dpp_add(float v) {
    int o = __builtin_amdgcn_update_dpp(0, __builtin_bit_cast(int, v),
                                        CTRL, 0xF, 0xF, true);
    return v + __builtin_bit_cast(float, o);
}

// Shared-memory union across phase bodies (36,864 B -> 4 blocks/CU by LDS).
union SharedU {
    struct { int2 pairs[CHUNK]; int bh[256]; int bbase[256]; int exb[256]; int scn[256]; } b;
    _Float16 w[128 * 136];
    struct { int lhist[256]; int lscan[256]; int lcur[256]; } s;
};

// ---------------------------------------------------------------------------
// chunk bucketing body (LDS counting-sort -> coalesced per-bucket flush)
// ---------------------------------------------------------------------------
__device__ __forceinline__ void bucket_chunk_body(
    SharedU& L, const int* __restrict__ ei, int* __restrict__ gcursor,
    int2* __restrict__ staging, int E, int bid)
{
    int t = threadIdx.x;
    L.b.bh[t] = 0;
    __syncthreads();
    int base = bid * CHUNK;
    int srcv[16], dstv[16], rb[16];
#pragma unroll
    for (int j = 0; j < 16; j++) {
        int e = base + t + j * 256;
        if (e < E) {
            int d = ei[E + e];
            srcv[j] = ei[e];
            dstv[j] = d;
            int bk = d >> 8;
            int r = atomicAdd(&L.b.bh[bk], 1);
            rb[j] = (r << 8) | bk;
        } else rb[j] = -1;
    }
    __syncthreads();
    int v = L.b.bh[t];
    L.b.scn[t] = v;
    __syncthreads();
    for (int off = 1; off < 256; off <<= 1) {
        int u = (t >= off) ? L.b.scn[t - off] : 0;
        __syncthreads();
        L.b.scn[t] += u;
        __syncthreads();
    }
    int ex = L.b.scn[t] - v;
    int tot = L.b.scn[255];
    L.b.exb[t] = ex;
    if (v) L.b.bbase[t] = t * BCAP + atomicAdd(&gcursor[t], v);
    __syncthreads();
#pragma unroll
    for (int j = 0; j < 16; j++) {
        if (rb[j] >= 0) {
            int bk = rb[j] & 255, r = rb[j] >> 8;
            L.b.pairs[L.b.exb[bk] + r] = make_int2(srcv[j], dstv[j]);
        }
    }
    __syncthreads();
    for (int i = t; i < tot; i += 256) {
        int2 p = L.b.pairs[i];
        int bk = p.y >> 8;
        staging[L.b.bbase[bk] + (i - L.b.exb[bk])] = p;
    }
}

// ---------------------------------------------------------------------------
// fp16 MFMA GEMM block body, ONE tile (r8-proven form; 2-tile variant
// regressed: VGPR 128 halved occupancy). C = Ah@W + Al@W, fp32 acc.
// ---------------------------------------------------------------------------
__device__ __forceinline__ void gemm_body(
    const _Float16* __restrict__ Ahi, const _Float16* __restrict__ Alo,
    const _Float16* __restrict__ Wt, _Float16* __restrict__ C, int N,
    int bx, _Float16* ldsW)
{
    const int tid = threadIdx.x;
    const int wave = tid >> 6;
    const int lane = tid & 63;
    const int mrow = lane & 15;
    const int quad = lane >> 4;
    const int rbase = bx * 128 + wave * 32;

    const int sn = tid >> 1, shf = tid & 1;
    float4 stg[8];
    {
        const float4* g = (const float4*)(Wt + sn * 128 + shf * 64);
#pragma unroll
        for (int j = 0; j < 8; j++) stg[j] = g[j];
    }

    f16x8 ah[2][4], al[2][4];
#pragma unroll
    for (int rt = 0; rt < 2; rt++) {
        int r = rbase + rt * 16 + mrow;
        if (r > N - 1) r = N - 1;
        const _Float16* pa = Ahi + (size_t)r * 128 + quad * 8;
        const _Float16* pl = Alo + (size_t)r * 128 + quad * 8;
#pragma unroll
        for (int s = 0; s < 4; s++) {
            ah[rt][s] = *(const f16x8*)(pa + s * 32);
            al[rt][s] = *(const f16x8*)(pl + s * 32);
        }
    }

    {
        float4* d = (float4*)&ldsW[sn * 136 + shf * 64];
#pragma unroll
        for (int j = 0; j < 8; j++) d[j] = stg[j];
    }

    f32x4 acc[2][8];
#pragma unroll
    for (int rt = 0; rt < 2; rt++)
#pragma unroll
        for (int c = 0; c < 8; c++) acc[rt][c] = (f32x4){0.f, 0.f, 0.f, 0.f};

    __syncthreads();

#pragma unroll
    for (int s = 0; s < 4; s++) {
#pragma unroll
        for (int c = 0; c < 8; c++) {
            f16x8 bw = *(const f16x8*)&ldsW[(c * 16 + mrow) * 136 + s * 32 + quad * 8];
            acc[0][c] = __builtin_amdgcn_mfma_f32_16x16x32_f16(ah[0][s], bw, acc[0][c], 0, 0, 0);
            acc[0][c] = __builtin_amdgcn_mfma_f32_16x16x32_f16(al[0][s], bw, acc[0][c], 0, 0, 0);
            acc[1][c] = __builtin_amdgcn_mfma_f32_16x16x32_f16(ah[1][s], bw, acc[1][c], 0, 0, 0);
            acc[1][c] = __builtin_amdgcn_mfma_f32_16x16x32_f16(al[1][s], bw, acc[1][c], 0, 0, 0);
        }
    }

    // D mapping: col = lane&15, row = quad*4 + reg
#pragma unroll
    for (int rt = 0; rt < 2; rt++)
#pragma unroll
        for (int i = 0; i < 4; i++) {
            int r = rbase + rt * 16 + quad * 4 + i;
            if (r < N) {
                _Float16* cr = C + (size_t)r * 128 + mrow;
#pragma unroll
                for (int c = 0; c < 8; c++) cr[c * 16] = (_Float16)acc[rt][c][i];
            }
        }
}

// ---------------------------------------------------------------------------
// per-bucket counting sort body -> start/deg/sorted_src (src<<8 byte offsets)
// ---------------------------------------------------------------------------
__device__ __forceinline__ void sort_bucket_body(
    SharedU& L, const int2* __restrict__ staging, const int* __restrict__ gcursor,
    int* __restrict__ start, int* __restrict__ deg,
    int* __restrict__ sorted_src, int N, int b)
{
    int t = threadIdx.x;
    int r0 = b * BCAP;
    int r1 = r0 + gcursor[b];
    L.s.lhist[t] = 0;
    __syncthreads();
    for (int i = r0 + t; i < r1; i += 256) atomicAdd(&L.s.lhist[staging[i].y & 255], 1);
    __syncthreads();
    int v = L.s.lhist[t];
    L.s.lscan[t] = v;
    __syncthreads();
    for (int off = 1; off < 256; off <<= 1) {
        int u = (t >= off) ? L.s.lscan[t - off] : 0;
        __syncthreads();
        L.s.lscan[t] += u;
        __syncthreads();
    }
    int excl = L.s.lscan[t] - v;
    int node = b * NPB + t;
    if (node < N) { start[node] = r0 + excl; deg[node] = v; }
    L.s.lcur[t] = excl;
    __syncthreads();
    for (int i = r0 + t; i < r1; i += 256) {
        int2 p = staging[i];
        int rank = atomicAdd(&L.s.lcur[p.y & 255], 1);
        sorted_src[r0 + rank] = p.x << 8;
    }
}

// ---------------------------------------------------------------------------
// Fused score+softmax+aggregate: grid-stride over node pairs (2 nodes/wave,
// lockstep groups, byte-offset gathers, group-0 self-loop specialization,
// v_exp2 softmax, DPP reduction). SINGLE-group pipeline steps with odd-K
// support: removes the even-rounding that processed ~21% masked slots
// (E[slots] 24.5 -> 21.3 per pair at Poisson(16) degrees).
// ---------------------------------------------------------------------------
template <int H, bool BFOUT>
__device__ __forceinline__ void fused_pairs_body(
    const _Float16* __restrict__ xl, const _Float16* __restrict__ xr,
    const float* __restrict__ att, const float* __restrict__ bias,
    const int* __restrict__ start, const int* __restrict__ deg,
    const int* __restrict__ sorted_src,
    float* __restrict__ outf, _Float16* __restrict__ oh,
    _Float16* __restrict__ ol, int N, int npairs)
{
    const int wid = threadIdx.x >> 6;
    const int lane = threadIdx.x & 63;
    const int g  = lane >> 4;
    const int hl = lane & 15;
    const unsigned hl16 = (unsigned)hl * 16;
    const _Float16 NS = (_Float16)NEG_SLOPE;
    const float L2E = 1.44269504f;

    float4 at0 = *(const float4*)(att + hl * 8);
    float4 at1 = *(const float4*)(att + hl * 8 + 4);
    float4 bi0 = *(const float4*)(bias + hl * 8);
    float4 bi1 = *(const float4*)(bias + hl * 8 + 4);
#if defined(HAVE_FDOT2)
    f16x2 av0 = {(_Float16)(at0.x * L2E), (_Float16)(at0.y * L2E)};
    f16x2 av1 = {(_Float16)(at0.z * L2E), (_Float16)(at0.w * L2E)};
    f16x2 av2 = {(_Float16)(at1.x * L2E), (_Float16)(at1.y * L2E)};
    f16x2 av3 = {(_Float16)(at1.z * L2E), (_Float16)(at1.w * L2E)};
#else
    f32x8 avf = {at0.x * L2E, at0.y * L2E, at0.z * L2E, at0.w * L2E,
                 at1.x * L2E, at1.y * L2E, at1.z * L2E, at1.w * L2E};
#endif

    auto score = [&](f16x8 a_, f16x8 b4_) -> float {
        f16x8 t = a_ + b4_;
        f16x8 u = __builtin_elementwise_max(t, t * NS);
#if defined(HAVE_FDOT2)
        f16x2 u0 = __builtin_shufflevector(u, u, 0, 1);
        f16x2 u1 = __builtin_shufflevector(u, u, 2, 3);
        f16x2 u2 = __builtin_shufflevector(u, u, 4, 5);
        f16x2 u3 = __builtin_shufflevector(u, u, 6, 7);
        return __builtin_amdgcn_fdot2(u0, av0,
               __builtin_amdgcn_fdot2(u1, av1,
               __builtin_amdgcn_fdot2(u2, av2,
               __builtin_amdgcn_fdot2(u3, av3, 0.f, false), false), false), false);
#else
        f32x8 uf = __builtin_convertvector(u, f32x8);
        float pp = 0.f;
#pragma unroll
        for (int i = 0; i < 8; i++) pp += uf[i] * avf[i];
        return pp;
#endif
    };

    auto red = [&](float v) -> float {
        v = dpp_add<0xB1>(v);
        v = dpp_add<0x4E>(v);
        v = dpp_add<0x141>(v);
        if (H == 1) v = dpp_add<0x140>(v);
        return v;
    };

    const unsigned cap = (unsigned)(N - 1) << 8;
    auto ldoff = [&](int pos) -> unsigned {
        unsigned v = (unsigned)sorted_src[pos];
        return (v < cap) ? v : cap;
    };
    auto grow = [&](unsigned off) -> f16x8 {
        return *(const f16x8*)((const char*)xl + (size_t)(off + hl16));
    };

    for (int p = blockIdx.x * 4 + wid; p < npairs; p += gridDim.x * 4) {
        const int n0 = 2 * p;
        const bool has1 = (n0 + 1) < N;
        const int n1 = has1 ? n0 + 1 : n0;
        const int s00 = start[n0], M0 = deg[n0] + 1;
        const int s01 = start[n1], M1 = deg[n1] + 1;

        const f16x8 b40 = *(const f16x8*)(xr + (size_t)n0 * 128 + hl * 8);
        const f16x8 b41 = *(const f16x8*)(xr + (size_t)n1 * 128 + hl * 8);

        const int Mmax = (M0 > M1) ? M0 : M1;
        int K = (Mmax + 3) >> 2;
        if (K < 2) K = 2;                 // pipeline prologue needs 2 groups

        f32x8 acc0 = {0.f, 0.f, 0.f, 0.f, 0.f, 0.f, 0.f, 0.f};
        f32x8 acc1 = {0.f, 0.f, 0.f, 0.f, 0.f, 0.f, 0.f, 0.f};
        float den0 = 0.f, den1 = 0.f;

        auto cone = [&](int kk, f16x8 a, f16x8 b4_, int M_, float& den_, f32x8& acc_) {
            float v = red(score(a, b4_));
            float e = (4 * kk + g < M_) ? FEXP2(v) : 0.f;
            den_ += e;
#pragma unroll
            for (int i = 0; i < 8; i++)
                acc_[i] = fmaf((float)a[i], e, acc_[i]);
        };

        // 2-deep pipeline, single-group steps (odd K supported).
        unsigned o00 = (g == 0) ? (unsigned)n0 << 8 : ldoff(s00 + g - 1);
        unsigned o01 = (g == 0) ? (unsigned)n1 << 8 : ldoff(s01 + g - 1);
        unsigned o10 = ldoff(s00 + g + 3);
        unsigned o11 = ldoff(s01 + g + 3);
        f16x8 c00 = grow(o00), c01 = grow(o01);   // group k-2 (both nodes)
        f16x8 c10 = grow(o10), c11 = grow(o11);   // group k-1
        for (int k = 2; k < K; k++) {
            unsigned p0 = ldoff(s00 + 4 * k + g - 1);
            unsigned p1 = ldoff(s01 + 4 * k + g - 1);
            f16x8 d0 = grow(p0), d1 = grow(p1);
            cone(k - 2, c00, b40, M0, den0, acc0);
            cone(k - 2, c01, b41, M1, den1, acc1);
            c00 = c10; c01 = c11;
            c10 = d0;  c11 = d1;
        }
        cone(K - 2, c00, b40, M0, den0, acc0);
        cone(K - 2, c01, b41, M1, den1, acc1);
        cone(K - 1, c10, b40, M0, den0, acc0);
        cone(K - 1, c11, b41, M1, den1, acc1);

        den0 += __shfl_xor(den0, 16, 64);
        den0 += __shfl_xor(den0, 32, 64);
        den1 += __shfl_xor(den1, 16, 64);
        den1 += __shfl_xor(den1, 32, 64);
#pragma unroll
        for (int i = 0; i < 8; i++) {
            acc0[i] += __shfl_xor(acc0[i], 16, 64);
            acc0[i] += __shfl_xor(acc0[i], 32, 64);
            acc1[i] += __shfl_xor(acc1[i], 16, 64);
            acc1[i] += __shfl_xor(acc1[i], 32, 64);
        }

        const int which = lane >> 4;
        if (which == 0 || (which == 1 && has1)) {
            float inv = 1.0f / (which == 0 ? den0 : den1);
            int nodeo = (which == 0) ? n0 : n1;
            float o[8];
#pragma unroll
            for (int i = 0; i < 8; i++) {
                float a = (which == 0) ? acc0[i] : acc1[i];
                float b = (i < 4) ? ((i == 0) ? bi0.x : (i == 1) ? bi0.y : (i == 2) ? bi0.z : bi0.w)
                                  : ((i == 4) ? bi1.x : (i == 5) ? bi1.y : (i == 6) ? bi1.z : bi1.w);
                o[i] = a * inv + b;
            }
            if (BFOUT) {
                f16x8 hv, lv;
#pragma unroll
                for (int i = 0; i < 8; i++) {
                    _Float16 h = (_Float16)o[i];
                    hv[i] = h;
                    lv[i] = (_Float16)(o[i] - (float)h);
                }
                *(f16x8*)(oh + (size_t)nodeo * 128 + hl * 8) = hv;
                *(f16x8*)(ol + (size_t)nodeo * 128 + hl * 8) = lv;
            } else {
                *(float4*)(outf + (size_t)nodeo * 128 + hl * 8) =
                    make_float4(o[0], o[1], o[2], o[3]);
                *(float4*)(outf + (size_t)nodeo * 128 + hl * 8 + 4) =
                    make_float4(o[4], o[5], o[6], o[7]);
            }
        }
    }
}

// ---------------------------------------------------------------------------
// K1: merged prep + bucketing.
// ---------------------------------------------------------------------------
__global__ __launch_bounds__(256) void k1_prep_bucket_kernel(
    const float* __restrict__ W0, const float* __restrict__ W1,
    const float* __restrict__ W2, const float* __restrict__ W3,
    _Float16* __restrict__ wt,
    const float* __restrict__ x, _Float16* __restrict__ xh,
    _Float16* __restrict__ xlo, int total,
    const int* __restrict__ ei, int* __restrict__ gcursor,
    int2* __restrict__ staging, int E, int B0)
{
    __shared__ SharedU lds;
    int t = threadIdx.x;
    int bid = blockIdx.x;
    if (bid < B0) {
        bucket_chunk_body(lds, ei, gcursor, staging, E, bid);
    } else if (bid < B0 + 256) {
        int idx = (bid - B0) * 256 + t;
        int m = idx >> 14, k = (idx >> 7) & 127, n = idx & 127;
        const float* W = (m == 0) ? W0 : (m == 1) ? W1 : (m == 2) ? W2 : W3;
        wt[m * 16384 + n * 128 + k] = (_Float16)W[k * 128 + n];
    } else {
        // x -> fp16 hi/lo split, float4-vectorized (G13)
        int i = (bid - B0 - 256) * 256 + t;
        if (i * 4 < total) {
            float4 f = *(const float4*)(x + (size_t)i * 4);
            _Float16 h0 = (_Float16)f.x, h1 = (_Float16)f.y;
            _Float16 h2 = (_Float16)f.z, h3 = (_Float16)f.w;
            f16x4 hv = {h0, h1, h2, h3};
            f16x4 lv = {(_Float16)(f.x - (float)h0), (_Float16)(f.y - (float)h1),
                        (_Float16)(f.z - (float)h2), (_Float16)(f.w - (float)h3)};
            *(f16x4*)(xh  + (size_t)i * 4) = hv;
            *(f16x4*)(xlo + (size_t)i * 4) = lv;
        }
    }
}

// ---------------------------------------------------------------------------
// K2: merged per-bucket counting sort + layer-1 GEMM (1 tile/block, r8 form).
//   blocks [0, NB)            : counting sort -> start/deg/sorted_src
//   blocks [NB, NB+gx)        : gemm y=0
//   blocks [NB+gx, NB+2*gx)   : gemm y=1
// ---------------------------------------------------------------------------
__global__ __launch_bounds__(256) void k2_sort_gemm_kernel(
    const int2* __restrict__ staging, const int* __restrict__ gcursor,
    int* __restrict__ start, int* __restrict__ deg,
    int* __restrict__ sorted_src, int N, int NBv,
    const _Float16* __restrict__ Ahi, const _Float16* __restrict__ Alo,
    const _Float16* __restrict__ Wt0, const _Float16* __restrict__ Wt1,
    _Float16* __restrict__ Cl, _Float16* __restrict__ Cr, int gx)
{
    __shared__ SharedU lds;
    int bx = blockIdx.x;
    if (bx < NBv) {
        sort_bucket_body(lds, staging, gcursor, start, deg, sorted_src, N, bx);
    } else {
        int gb = bx - NBv;
        int y = (gb >= gx) ? 1 : 0;
        gemm_body(Ahi, Alo, y ? Wt1 : Wt0, y ? Cr : Cl, N, y ? gb - gx : gb, lds.w);
    }
}

// standalone GEMM (layer 2): blockIdx.y selects W/output, 1 tile/block
__global__ __launch_bounds__(256) void gemm_f16_kernel(
    const _Float16* __restrict__ Ahi, const _Float16* __restrict__ Alo,
    const _Float16* __restrict__ Wt0, const _Float16* __restrict__ Wt1,
    _Float16* __restrict__ Cl, _Float16* __restrict__ Cr, int N)
{
    __shared__ SharedU lds;
    gemm_body(Ahi, Alo, blockIdx.y ? Wt1 : Wt0, blockIdx.y ? Cr : Cl, N,
              blockIdx.x, lds.w);
}

template <int H, bool BFOUT>
__global__ __launch_bounds__(256) void gat_fused_kernel(
    const _Float16* __restrict__ xl, const _Float16* __restrict__ xr,
    const float* __restrict__ att, const float* __restrict__ bias,
    const int* __restrict__ start, const int* __restrict__ deg,
    const int* __restrict__ sorted_src,
    float* __restrict__ outf, _Float16* __restrict__ oh,
    _Float16* __restrict__ ol, int N, int npairs)
{
    fused_pairs_body<H, BFOUT>(xl, xr, att, bias, start, deg, sorted_src,
                               outf, oh, ol, N, npairs);
}

// ---------------------------------------------------------------------------
extern "C" void kernel_launch(void* const* d_in, const int* in_sizes, int n_in,
                              void* d_out, int out_size, void* d_ws, size_t ws_size,
                              hipStream_t stream)
{
    const float* x    = (const float*)d_in[0];
    const int*   ei   = (const int*)d_in[1];
    const float* Wl1  = (const float*)d_in[3];
    const float* Wr1  = (const float*)d_in[4];
    const float* att1 = (const float*)d_in[5];
    const float* b1   = (const float*)d_in[6];
    const float* Wl2  = (const float*)d_in[7];
    const float* Wr2  = (const float*)d_in[8];
    const float* att2 = (const float*)d_in[9];
    const float* b2   = (const float*)d_in[10];
    float* out = (float*)d_out;

    const int N  = in_sizes[0] / 128;
    const int E  = in_sizes[1] / 2;
    const int NB = (N + NPB - 1) / NPB;

    const size_t nf = (size_t)N * 128;
    _Float16* xlf  = (_Float16*)d_ws;
    _Float16* xrf  = xlf + nf;
    _Float16* ah   = xrf + nf;
    _Float16* al   = ah + nf;
    _Float16* wt   = al + nf;
    int* gcursor   = (int*)(wt + 4 * 16384);
    int* start     = gcursor + 256;
    int* deg       = start + N;
    size_t stgoff  = ((size_t)(deg + N) + 7) & ~(size_t)7;
    int2* staging  = (int2*)stgoff;
    int* sorted_src = (int*)(staging + (size_t)NB * BCAP);

    const int grid_chunk = (E + CHUNK - 1) / CHUNK;
    const int npairs     = (N + 1) / 2;
    const int gemm_gx    = (N + 127) / 128;
    const int split_grid = (int)((nf / 4 + 255) / 256);

    int node_grid = (npairs + 3) / 4;
    if (node_grid > 2048) node_grid = 2048;           // persistent grid-stride

    // ---- zero bucket cursors ----
    hipMemsetAsync(gcursor, 0, 256 * sizeof(int), stream);

    // ---- K1: prep (W fp16-transpose, x hi/lo split) + chunk bucketing ----
    k1_prep_bucket_kernel<<<grid_chunk + 256 + split_grid, 256, 0, stream>>>(
        Wl1, Wr1, Wl2, Wr2, wt, x, ah, al, (int)nf,
        ei, gcursor, staging, E, grid_chunk);

    // ---- K2: per-bucket counting sort + layer-1 GEMM (both halves) ----
    k2_sort_gemm_kernel<<<NB + 2 * gemm_gx, 256, 0, stream>>>(
        staging, gcursor, start, deg, sorted_src, N, NB,
        ah, al, wt + 0 * 16384, wt + 1 * 16384, xlf, xrf, gemm_gx);

    // ---- Layer 1 fused ----
    gat_fused_kernel<2, true><<<node_grid, 256, 0, stream>>>(
        xlf, xrf, att1, b1, start, deg, sorted_src, nullptr, ah, al, N, npairs);

    // ---- Layer 2: GEMM + fused ----
    gemm_f16_kernel<<<dim3(gemm_gx, 2), 256, 0, stream>>>(
        ah, al, wt + 2 * 16384, wt + 3 * 16384, xlf, xrf, N);
    gat_fused_kernel<1, false><<<node_grid, 256, 0, stream>>>(
        xlf, xrf, att2, b2, start, deg, sorted_src, out, nullptr, nullptr, N, npairs);
}